// Round 1
// baseline (129.168 us; speedup 1.0000x reference)
//
#include <hip/hip_runtime.h>

// NeighborPruning: LayerNorm over a size-1 axis makes every score identically
// ln_beta (mean==s, var==0 -> 0*gamma+beta). All regular edges tie; stable
// lexsort => within each dst, top-3 regular edges are the 3 with smallest
// original edge index. Self loops kept unconditionally.

#define TOPK 3

// Insert regular edge indices into per-dst 3-slot atomic-min cascade.
__global__ void np_insert(const int* __restrict__ src,
                          const int* __restrict__ dst,
                          unsigned int* __restrict__ slots, int E) {
    int e = blockIdx.x * blockDim.x + threadIdx.x;
    if (e >= E) return;
    int s = src[e];
    int d = dst[e];
    if (s == d) return;  // self loops excluded from ranking
    unsigned int val = (unsigned int)e;
    unsigned int* base = slots + 3u * (unsigned int)d;
#pragma unroll
    for (int k = 0; k < TOPK; ++k) {
        unsigned int old = atomicMin(&base[k], val);
        // carry the displaced (larger) value to the next slot
        val = (old > val) ? old : val;
        if (val == 0xFFFFFFFFu) break;  // hit an empty slot; nothing left to push
    }
}

// keep[e] = self || (e is one of the 3 smallest regular-edge indices of dst[e])
// scores[e] = ln_beta (LayerNorm over size-1 axis collapses to beta)
__global__ void np_output(const int* __restrict__ src,
                          const int* __restrict__ dst,
                          const unsigned int* __restrict__ slots,
                          const float* __restrict__ ln_beta,
                          float* __restrict__ keep_out,
                          float* __restrict__ score_out, int E) {
    int e = blockIdx.x * blockDim.x + threadIdx.x;
    if (e >= E) return;
    int s = src[e];
    int d = dst[e];
    bool self = (s == d);
    const unsigned int* base = slots + 3u * (unsigned int)d;
    unsigned int ue = (unsigned int)e;
    bool member = (base[0] == ue) | (base[1] == ue) | (base[2] == ue);
    keep_out[e] = (self || member) ? 1.0f : 0.0f;
    score_out[e] = ln_beta[0];
}

extern "C" void kernel_launch(void* const* d_in, const int* in_sizes, int n_in,
                              void* d_out, int out_size, void* d_ws, size_t ws_size,
                              hipStream_t stream) {
    // inputs (setup_inputs order):
    // 0:h [N,64] f32  1:q [B,64] f32  2:edge_index [2,E] int  3:edge_batch [E] int
    // 4:W1  5:b1  6:W2  7:b2  8:ln_gamma [1]  9:ln_beta [1]
    const int* edge_index = (const int*)d_in[2];
    const float* ln_beta  = (const float*)d_in[9];
    const int E = in_sizes[3];
    const int N = in_sizes[0] / 64;

    const int* src = edge_index;       // row 0
    const int* dst = edge_index + E;   // row 1

    float* keep_out  = (float*)d_out;       // first E floats: keep (0/1)
    float* score_out = (float*)d_out + E;   // next E floats: scores

    unsigned int* slots = (unsigned int*)d_ws;  // N*3 uints = 600 KB
    size_t slots_bytes = (size_t)N * 3 * sizeof(unsigned int);

    hipMemsetAsync(slots, 0xFF, slots_bytes, stream);  // sentinel = UINT_MAX

    const int block = 256;
    const int grid = (E + block - 1) / block;
    np_insert<<<grid, block, 0, stream>>>(src, dst, slots, E);
    np_output<<<grid, block, 0, stream>>>(src, dst, slots, ln_beta,
                                          keep_out, score_out, E);
}

// Round 2
// 124.114 us; speedup vs baseline: 1.0407x; 1.0407x over previous
//
#include <hip/hip_runtime.h>

// NeighborPruning: LayerNorm over a size-1 axis makes every score identically
// ln_beta. All regular edges tie; stable lexsort => per-dst top-3 = the 3
// smallest original edge indices among regular (non-self-loop) edges.
// Self loops kept unconditionally.
//
// R2: packed 64-bit lock-free top-3 per dst. Three 21-bit sorted fields
// (s0<=s1<=s2) in one u64; E=400k < 2^21; sentinel 0x1FFFFF comes free from
// memset 0xFF. Losing edges do ONE plain 8B read (L2-hot, 400KB state) and no
// atomics; winners do one atomicCAS. Stale reads are safe: fields only
// decrease, so stale >= current and v >= stale_s2 implies a genuine loss.

#define SENT21 0x1FFFFFu

__device__ __forceinline__ unsigned long long pack3(unsigned a, unsigned b, unsigned c) {
    return ((unsigned long long)a << 42) | ((unsigned long long)b << 21) | (unsigned long long)c;
}

__global__ void np_insert(const int* __restrict__ src,
                          const int* __restrict__ dst,
                          unsigned long long* __restrict__ slots,
                          const float* __restrict__ ln_beta,
                          float* __restrict__ score_out, int E) {
    int e = blockIdx.x * blockDim.x + threadIdx.x;
    if (e >= E) return;
    int s = src[e];
    int d = dst[e];
    score_out[e] = ln_beta[0];          // LayerNorm(size-1) == beta, always
    if (s == d) return;                 // self loops excluded from ranking
    unsigned v = (unsigned)e;
    unsigned long long* p = slots + (unsigned)d;
    unsigned long long cur = *p;        // plain read; staleness is direction-safe
    for (;;) {
        unsigned s0 = (unsigned)(cur >> 42) & SENT21;
        unsigned s1 = (unsigned)(cur >> 21) & SENT21;
        unsigned s2 = (unsigned)(cur      ) & SENT21;
        if (v >= s2) break;             // cannot enter top-3 (indices unique)
        unsigned n0, n1, n2;
        if (v < s0)      { n0 = v;  n1 = s0; n2 = s1; }
        else if (v < s1) { n0 = s0; n1 = v;  n2 = s1; }
        else             { n0 = s0; n1 = s1; n2 = v;  }
        unsigned long long ns = pack3(n0, n1, n2);
        unsigned long long prev = atomicCAS(p, cur, ns);
        if (prev == cur) break;         // installed
        cur = prev;                     // lost race; retry with fresh state
    }
}

__global__ void np_output(const int* __restrict__ src,
                          const int* __restrict__ dst,
                          const unsigned long long* __restrict__ slots,
                          float* __restrict__ keep_out, int E) {
    int e = blockIdx.x * blockDim.x + threadIdx.x;
    if (e >= E) return;
    int s = src[e];
    int d = dst[e];
    unsigned long long st = slots[(unsigned)d];
    unsigned v = (unsigned)e;
    bool member = (((unsigned)(st >> 42) & SENT21) == v) |
                  (((unsigned)(st >> 21) & SENT21) == v) |
                  (((unsigned)(st      ) & SENT21) == v);
    keep_out[e] = (s == d || member) ? 1.0f : 0.0f;
}

extern "C" void kernel_launch(void* const* d_in, const int* in_sizes, int n_in,
                              void* d_out, int out_size, void* d_ws, size_t ws_size,
                              hipStream_t stream) {
    // inputs: 0:h [N,64] 1:q 2:edge_index [2,E] int 3:edge_batch [E]
    //         4:W1 5:b1 6:W2 7:b2 8:ln_gamma 9:ln_beta
    const int* edge_index = (const int*)d_in[2];
    const float* ln_beta  = (const float*)d_in[9];
    const int E = in_sizes[3];
    const int N = in_sizes[0] / 64;

    const int* src = edge_index;       // row 0
    const int* dst = edge_index + E;   // row 1

    float* keep_out  = (float*)d_out;       // first E floats: keep (0/1)
    float* score_out = (float*)d_out + E;   // next E floats: scores

    unsigned long long* slots = (unsigned long long*)d_ws;   // N u64 = 400 KB
    hipMemsetAsync(slots, 0xFF, (size_t)N * sizeof(unsigned long long), stream);

    const int block = 256;
    const int grid = (E + block - 1) / block;
    np_insert<<<grid, block, 0, stream>>>(src, dst, slots, ln_beta, score_out, E);
    np_output<<<grid, block, 0, stream>>>(src, dst, slots, keep_out, E);
}

// Round 3
// 114.077 us; speedup vs baseline: 1.1323x; 1.0880x over previous
//
#include <hip/hip_runtime.h>

// NeighborPruning: LayerNorm over a size-1 axis makes every score identically
// ln_beta. All regular edges tie; stable lexsort => per-dst top-3 = the 3
// smallest original edge indices among regular (non-self-loop) edges.
// Self loops kept unconditionally.
//
// R3: device atomic pipe (~25 G ops/s) is the measured bottleneck, so minimize
// runtime atomics:
//  - Kernel A uses a SMALL grid-stride sweep (64k threads) so edges are
//    processed in near-ascending index order. The plain-read filter is then
//    warm: an edge CASes only if it's among the first <=3 of its dst seen so
//    far -> ~150k CAS total, near-zero contention.
//  - Kernel B iterates DSTS (50k, coalesced slot reads) and scatter-writes
//    keep=1 for the <=3 winners, replacing the 400k random membership gather.

#define SENT21 0x1FFFFFu

__device__ __forceinline__ unsigned long long pack3(unsigned a, unsigned b, unsigned c) {
    return ((unsigned long long)a << 42) | ((unsigned long long)b << 21) | (unsigned long long)c;
}

__global__ void np_insert(const int* __restrict__ src,
                          const int* __restrict__ dst,
                          unsigned long long* __restrict__ slots,
                          const float* __restrict__ ln_beta,
                          float* __restrict__ keep_out,
                          float* __restrict__ score_out, int E) {
    const float beta = ln_beta[0];
    const int stride = gridDim.x * blockDim.x;
    for (int e = blockIdx.x * blockDim.x + threadIdx.x; e < E; e += stride) {
        int s = src[e];
        int d = dst[e];
        score_out[e] = beta;                 // LayerNorm(size-1) == beta, always
        bool self = (s == d);
        keep_out[e] = self ? 1.0f : 0.0f;    // winners promoted to 1 by np_scatter
        if (self) continue;                  // self loops excluded from ranking
        unsigned v = (unsigned)e;
        unsigned long long* p = slots + (unsigned)d;
        unsigned long long cur = *p;         // warm filter: stale reads direction-safe
        while (v < ((unsigned)cur & SENT21)) {   // v < s2 ?
            unsigned s0 = (unsigned)(cur >> 42) & SENT21;
            unsigned s1 = (unsigned)(cur >> 21) & SENT21;
            unsigned s2 = (unsigned)(cur      ) & SENT21;
            unsigned n0, n1, n2;
            if (v < s0)      { n0 = v;  n1 = s0; n2 = s1; }
            else if (v < s1) { n0 = s0; n1 = v;  n2 = s1; }
            else             { n0 = s0; n1 = s1; n2 = v;  }
            unsigned long long prev = atomicCAS(p, cur, pack3(n0, n1, n2));
            if (prev == cur) break;          // installed
            cur = prev;                      // lost race; recheck with fresh state
        }
    }
}

// One thread per dst: coalesced slot read, scatter keep=1 to the <=3 winners.
__global__ void np_scatter(const unsigned long long* __restrict__ slots,
                           float* __restrict__ keep_out, int N) {
    int d = blockIdx.x * blockDim.x + threadIdx.x;
    if (d >= N) return;
    unsigned long long st = slots[d];
    unsigned s0 = (unsigned)(st >> 42) & SENT21;
    unsigned s1 = (unsigned)(st >> 21) & SENT21;
    unsigned s2 = (unsigned)(st      ) & SENT21;
    if (s0 != SENT21) keep_out[s0] = 1.0f;
    if (s1 != SENT21) keep_out[s1] = 1.0f;
    if (s2 != SENT21) keep_out[s2] = 1.0f;
}

extern "C" void kernel_launch(void* const* d_in, const int* in_sizes, int n_in,
                              void* d_out, int out_size, void* d_ws, size_t ws_size,
                              hipStream_t stream) {
    // inputs: 0:h [N,64] 1:q 2:edge_index [2,E] int 3:edge_batch [E]
    //         4:W1 5:b1 6:W2 7:b2 8:ln_gamma 9:ln_beta
    const int* edge_index = (const int*)d_in[2];
    const float* ln_beta  = (const float*)d_in[9];
    const int E = in_sizes[3];
    const int N = in_sizes[0] / 64;

    const int* src = edge_index;       // row 0
    const int* dst = edge_index + E;   // row 1

    float* keep_out  = (float*)d_out;       // first E floats: keep (0/1)
    float* score_out = (float*)d_out + E;   // next E floats: scores

    unsigned long long* slots = (unsigned long long*)d_ws;   // N u64 = 400 KB
    hipMemsetAsync(slots, 0xFF, (size_t)N * sizeof(unsigned long long), stream);

    const int block = 256;
    // Small grid + grid-stride: near-ascending edge order keeps the CAS filter
    // warm (atomic count ~= min(3,deg) per dst instead of ~1M).
    np_insert<<<256, block, 0, stream>>>(src, dst, slots, ln_beta,
                                         keep_out, score_out, E);
    np_scatter<<<(N + block - 1) / block, block, 0, stream>>>(slots, keep_out, N);
}

// Round 4
// 111.850 us; speedup vs baseline: 1.1548x; 1.0199x over previous
//
#include <hip/hip_runtime.h>

// NeighborPruning: LayerNorm over a size-1 axis makes every score identically
// ln_beta. All regular edges tie; stable lexsort => per-dst top-3 = the 3
// smallest original edge indices among regular (non-self-loop) edges.
// Self loops kept unconditionally.
//
// R4 structure (atomic pipe + latency are the levers; streaming work split out):
//  1) np_write  — full grid over E: score=beta, keep=self?1:0 (coalesced
//     streaming, ~2us), first N threads also init slots to sentinel (replaces
//     the separate hipMemsetAsync dispatch).
//  2) np_insert — 64k-thread grid-stride sweep => edges arrive in ascending
//     64k-windows, so the plain-read filter stays warm (~150-200k CAS total).
//     Next-window src/dst prefetched while current slot read/CAS resolves.
//  3) np_scatter — one thread per dst, coalesced slot read, scatter keep=1
//     to the <=3 winners.

#define SENT21 0x1FFFFFu

__device__ __forceinline__ unsigned long long pack3(unsigned a, unsigned b, unsigned c) {
    return ((unsigned long long)a << 42) | ((unsigned long long)b << 21) | (unsigned long long)c;
}

// Full-grid streaming pass: outputs + slot init.
__global__ void np_write(const int* __restrict__ src,
                         const int* __restrict__ dst,
                         const float* __restrict__ ln_beta,
                         unsigned long long* __restrict__ slots,
                         float* __restrict__ keep_out,
                         float* __restrict__ score_out, int E, int N) {
    int t = blockIdx.x * blockDim.x + threadIdx.x;
    if (t < N) slots[t] = ~0ULL;                    // sentinel (s0=s1=s2=SENT21)
    if (t >= E) return;
    score_out[t] = ln_beta[0];                      // LayerNorm(size-1) == beta
    keep_out[t] = (src[t] == dst[t]) ? 1.0f : 0.0f; // winners promoted later
}

// Ordered-window CAS insert. Thread count (64k) == window width: edges are
// globally processed in ascending 64k-index windows, keeping the read filter
// warm. Stale reads are direction-safe (fields only decrease).
__global__ void np_insert(const int* __restrict__ src,
                          const int* __restrict__ dst,
                          unsigned long long* __restrict__ slots, int E) {
    const int stride = gridDim.x * blockDim.x;
    int e = blockIdx.x * blockDim.x + threadIdx.x;
    if (e >= E) return;
    int s = src[e];
    int d = dst[e];
    for (;;) {
        // Prefetch next window's edge while this one's slot traffic resolves.
        int e_next = e + stride;
        int s_next = 0, d_next = 0;
        bool have_next = (e_next < E);
        if (have_next) { s_next = src[e_next]; d_next = dst[e_next]; }

        if (s != d) {
            unsigned v = (unsigned)e;
            unsigned long long* p = slots + (unsigned)d;
            unsigned long long cur = *p;            // warm filter, no atomic
            while (v < ((unsigned)cur & SENT21)) {  // v < s2 ?
                unsigned s0 = (unsigned)(cur >> 42) & SENT21;
                unsigned s1 = (unsigned)(cur >> 21) & SENT21;
                unsigned n0, n1, n2;
                if (v < s0)      { n0 = v;  n1 = s0; n2 = s1; }
                else if (v < s1) { n0 = s0; n1 = v;  n2 = s1; }
                else             { n0 = s0; n1 = s1; n2 = v;  }
                unsigned long long prev = atomicCAS(p, cur, pack3(n0, n1, n2));
                if (prev == cur) break;             // installed
                cur = prev;                         // lost race; recheck
            }
        }
        if (!have_next) break;
        e = e_next; s = s_next; d = d_next;
    }
}

// One thread per dst: coalesced slot read, scatter keep=1 to the <=3 winners.
__global__ void np_scatter(const unsigned long long* __restrict__ slots,
                           float* __restrict__ keep_out, int N) {
    int d = blockIdx.x * blockDim.x + threadIdx.x;
    if (d >= N) return;
    unsigned long long st = slots[d];
    unsigned s0 = (unsigned)(st >> 42) & SENT21;
    unsigned s1 = (unsigned)(st >> 21) & SENT21;
    unsigned s2 = (unsigned)(st      ) & SENT21;
    if (s0 != SENT21) keep_out[s0] = 1.0f;
    if (s1 != SENT21) keep_out[s1] = 1.0f;
    if (s2 != SENT21) keep_out[s2] = 1.0f;
}

extern "C" void kernel_launch(void* const* d_in, const int* in_sizes, int n_in,
                              void* d_out, int out_size, void* d_ws, size_t ws_size,
                              hipStream_t stream) {
    // inputs: 0:h [N,64] 1:q 2:edge_index [2,E] int 3:edge_batch [E]
    //         4:W1 5:b1 6:W2 7:b2 8:ln_gamma 9:ln_beta
    const int* edge_index = (const int*)d_in[2];
    const float* ln_beta  = (const float*)d_in[9];
    const int E = in_sizes[3];
    const int N = in_sizes[0] / 64;

    const int* src = edge_index;       // row 0
    const int* dst = edge_index + E;   // row 1

    float* keep_out  = (float*)d_out;       // first E floats: keep (0/1)
    float* score_out = (float*)d_out + E;   // next E floats: scores

    unsigned long long* slots = (unsigned long long*)d_ws;   // N u64 = 400 KB

    const int block = 256;
    np_write<<<(E + block - 1) / block, block, 0, stream>>>(
        src, dst, ln_beta, slots, keep_out, score_out, E, N);
    // 256 blocks x 256 threads = 64k window; ordering keeps CAS count ~150k.
    np_insert<<<256, block, 0, stream>>>(src, dst, slots, E);
    np_scatter<<<(N + block - 1) / block, block, 0, stream>>>(slots, keep_out, N);
}